// Round 3
// baseline (220.396 us; speedup 1.0000x reference)
//
#include <hip/hip_runtime.h>
#include <hip/hip_bf16.h>

// Problem constants (P=1 folded out everywhere)
#define NB   8      // batch
#define NA   8      // actions
#define ND   8      // dim_qk
#define NCH  64     // NA*ND q/k channels
#define GT   32     // grid T=H=W
#define KREG 216    // 6*6*6 k/v halo region voxels
#define KSTR 68     // kS row stride in floats (16B aligned, bank-spread)
#define VSTR 9      // vS row stride (gcd(9,32)=1 -> bank-spread)
#define WROW 28     // weight row: 27 taps + 1 zero pad (16B-aligned rows)

// ws layout (floats): wq [128][WROW] @0, wv [8][WROW] @WV_OFF, dtype flag @FLAG_OFF
#define WV_OFF   (128 * WROW)          // 3584
#define FLAG_OFF (WV_OFF + 8 * WROW)   // 3808

__global__ void prep_weights(const void* __restrict__ values,
                             const void* __restrict__ w_qk,
                             const void* __restrict__ w_v,
                             float* __restrict__ ws) {
    __shared__ int saneCnt;
    int t = threadIdx.x;  // 0..127
    if (t == 0) saneCnt = 0;
    __syncthreads();

    // ---- input dtype detection (robustness armor; expect fp32) ----
    // fp32 N(0,1) read as u16 pairs: high halves sane exponents, low halves
    // ~20% sane -> cnt ~154. True bf16 storage: ~256. Threshold 230.
    {
        const unsigned short* u16 = (const unsigned short*)values;
        int cnt = 0;
        for (int j = 0; j < 2; ++j) {
            unsigned short u = u16[((t * 2 + j) * 911) & (262144 - 1)];
            int e = (u >> 7) & 0xFF;
            if (e == 0 || (e >= 100 && e <= 150)) cnt++;
        }
        atomicAdd(&saneCnt, cnt);
    }
    __syncthreads();
    const bool isbf = (saneCnt >= 230);
    if (t == 0) ws[FLAG_OFF] = isbf ? 1.f : 0.f;

    // ---- w_qk rows -> fp32, padded to WROW ----
    if (isbf) {
        const __hip_bfloat16* w = (const __hip_bfloat16*)w_qk;
        for (int j = 0; j < 27; ++j)
            ws[t * WROW + j] = __bfloat162float(w[t * 27 + j]);
    } else {
        const float* w = (const float*)w_qk;
        for (int j = 0; j < 27; ++j)
            ws[t * WROW + j] = w[t * 27 + j];
    }
    ws[t * WROW + 27] = 0.f;

    // ---- softmax(w_v) rows ----
    if (t < NA) {
        float r[27], m = -1e30f;
        if (isbf) {
            const __hip_bfloat16* w = (const __hip_bfloat16*)w_v;
            for (int j = 0; j < 27; ++j) r[j] = __bfloat162float(w[t * 27 + j]);
        } else {
            const float* w = (const float*)w_v;
            for (int j = 0; j < 27; ++j) r[j] = w[t * 27 + j];
        }
        for (int j = 0; j < 27; ++j) m = fmaxf(m, r[j]);
        float s = 0.f;
        for (int j = 0; j < 27; ++j) { r[j] = __expf(r[j] - m); s += r[j]; }
        float inv = 1.f / s;
        for (int j = 0; j < 27; ++j) ws[WV_OFF + t * WROW + j] = r[j] * inv;
        ws[WV_OFF + t * WROW + 27] = 0.f;
    }
}

__launch_bounds__(256, 2)
__global__ void avi_kernel(const void* __restrict__ values,
                           const void* __restrict__ rewards,
                           const float* __restrict__ ws,
                           float* __restrict__ out) {
    __shared__ __align__(16) float xS[512];          // 8^3 x tile, origin g0-2
    __shared__ __align__(16) float kS[KREG * KSTR];  // [216][68] k channels
    __shared__ __align__(16) float vS[KREG * VSTR];  // [216][9]  v channels
    __shared__ __align__(16) float outP[64 * 4];     // cross-wave max buffer

    const int tid  = threadIdx.x;
    const int bb   = blockIdx.x >> 9;      // batch
    const int tile = blockIdx.x & 511;     // 8x8x8 tiles of 4^3
    const int tz = tile >> 6, ty = (tile >> 3) & 7, tx = tile & 7;
    const int g0z = tz * 4, g0y = ty * 4, g0x = tx * 4;
    const int base_in = bb * (GT * GT * GT);

    const bool isbf = (ws[FLAG_OFF] != 0.f);  // uniform branch

    // ---- Phase A: stage x = values + rewards (fp32), zero outside grid ----
    for (int i = tid; i < 512; i += 256) {
        int lz = i >> 6, ly = (i >> 3) & 7, lx = i & 7;
        int gz = g0z + lz - 2, gy = g0y + ly - 2, gx = g0x + lx - 2;
        float v = 0.f;
        if ((unsigned)gz < 32u && (unsigned)gy < 32u && (unsigned)gx < 32u) {
            int idx = base_in + gz * 1024 + gy * 32 + gx;
            if (isbf) {
                v = __bfloat162float(((const __hip_bfloat16*)values)[idx]) +
                    __bfloat162float(((const __hip_bfloat16*)rewards)[idx]);
            } else {
                v = ((const float*)values)[idx] + ((const float*)rewards)[idx];
            }
        }
        xS[i] = v;
    }
    __syncthreads();

    // ---- Phase B: k/v conv over 6^3 halo region (origin g0-1) ----
    if (tid < KREG) {
        int vz = tid / 36, rem = tid - vz * 36, vy = rem / 6, vx = rem - vy * 6;
        int gz = g0z + vz - 1, gy = g0y + vy - 1, gx = g0x + vx - 1;
        // k/v outside the global grid are exactly 0 (padding of conv OUTPUT)
        float mask = ((unsigned)gz < 32u && (unsigned)gy < 32u && (unsigned)gx < 32u)
                         ? 1.f : 0.f;
        float xr[WROW];
        #pragma unroll
        for (int t = 0; t < 27; ++t) {
            int dz = t / 9, dy = (t / 3) % 3, dx = t % 3;
            xr[t] = xS[(vz + dz) * 64 + (vy + dy) * 8 + (vx + dx)];
        }
        xr[27] = 0.f;
        // k channels: w_qk rows 64..127 (second half = k weights)
        const float* wk = ws + NCH * WROW;
        int kbase = tid * KSTR;
        for (int c4 = 0; c4 < 16; ++c4) {
            float4 o;
            #pragma unroll
            for (int j = 0; j < 4; ++j) {
                const float* w = wk + (c4 * 4 + j) * WROW;
                float acc = 0.f;
                #pragma unroll
                for (int t = 0; t < WROW; ++t) acc = fmaf(w[t], xr[t], acc);
                ((float*)&o)[j] = acc * mask;
            }
            *(float4*)(kS + kbase + c4 * 4) = o;
        }
        // v channels (softmaxed weights)
        #pragma unroll
        for (int c = 0; c < NA; ++c) {
            const float* w = ws + WV_OFF + c * WROW;
            float acc = 0.f;
            #pragma unroll
            for (int t = 0; t < WROW; ++t) acc = fmaf(w[t], xr[t], acc);
            vS[tid * VSTR + c] = acc * mask;
        }
    }
    __syncthreads();

    // ---- Phase C: q + neighborhood attention; a = waveId(+4), voxel = lane ----
    const int lane = tid & 63;
    const int wave = tid >> 6;
    const int lz = lane >> 4, ly = (lane >> 2) & 3, lx = lane & 3;

    // x taps for q at this voxel (shared by both a-tasks)
    float xr[WROW];
    #pragma unroll
    for (int t = 0; t < 27; ++t) {
        int dz = t / 9, dy = (t / 3) % 3, dx = t % 3;
        xr[t] = xS[(lz + 1 + dz) * 64 + (ly + 1 + dy) * 8 + (lx + 1 + dx)];
    }
    xr[27] = 0.f;

    float res[2];
    #pragma unroll
    for (int ti = 0; ti < 2; ++ti) {
        int a = wave + ti * 4;   // wave-uniform -> scalar weight loads
        const float* wq = ws + a * ND * WROW;  // q weights: rows 0..63
        float q[ND];
        #pragma unroll
        for (int d = 0; d < ND; ++d) {
            float acc = 0.f;
            #pragma unroll
            for (int t = 0; t < WROW; ++t) acc = fmaf(wq[d * WROW + t], xr[t], acc);
            q[d] = acc;
        }
        float sim[27];
        float m = -1e30f;
        #pragma unroll
        for (int n = 0; n < 27; ++n) {
            int dz = n / 9, dy = (n / 3) % 3, dx = n % 3;
            int kn = (lz + dz) * 36 + (ly + dy) * 6 + (lx + dx);
            const float4* kp = (const float4*)(kS + kn * KSTR + a * ND);
            float4 k0 = kp[0], k1 = kp[1];
            float s = q[0] * k0.x;
            s = fmaf(q[1], k0.y, s);
            s = fmaf(q[2], k0.z, s);
            s = fmaf(q[3], k0.w, s);
            s = fmaf(q[4], k1.x, s);
            s = fmaf(q[5], k1.y, s);
            s = fmaf(q[6], k1.z, s);
            s = fmaf(q[7], k1.w, s);
            sim[n] = s;
            m = fmaxf(m, s);
        }
        float ssum = 0.f, acc = 0.f;
        #pragma unroll
        for (int n = 0; n < 27; ++n) {
            int dz = n / 9, dy = (n / 3) % 3, dx = n % 3;
            int kn = (lz + dz) * 36 + (ly + dy) * 6 + (lx + dx);
            float e = __expf(sim[n] - m);
            ssum += e;
            acc = fmaf(e, vS[kn * VSTR + a], acc);
        }
        res[ti] = acc / ssum;
    }
    outP[lane * 4 + wave] = fmaxf(res[0], res[1]);
    __syncthreads();

    // ---- max over actions (4 wave-partials) -> FP32 output ----
    if (tid < 64) {
        float4 p = *(const float4*)(outP + tid * 4);
        float mx = fmaxf(fmaxf(p.x, p.y), fmaxf(p.z, p.w));
        int lz2 = tid >> 4, ly2 = (tid >> 2) & 3, lx2 = tid & 3;
        int o = base_in + (g0z + lz2) * 1024 + (g0y + ly2) * 32 + (g0x + lx2);
        out[o] = mx;   // fp32 store: d_out is float* per the reference contract
    }
}

extern "C" void kernel_launch(void* const* d_in, const int* in_sizes, int n_in,
                              void* d_out, int out_size, void* d_ws, size_t ws_size,
                              hipStream_t stream) {
    const void* values  = d_in[0];
    const void* rewards = d_in[1];
    const void* w_qk    = d_in[2];
    const void* w_v     = d_in[3];
    float* ws = (float*)d_ws;  // 15236 B used

    prep_weights<<<1, 128, 0, stream>>>(values, w_qk, w_v, ws);
    avi_kernel<<<NB * 512, 256, 0, stream>>>(values, rewards, ws,
                                             (float*)d_out);
}